// Round 21
// baseline (199.883 us; speedup 1.0000x reference)
//
#include <hip/hip_runtime.h>
#include <cstdint>

#define D 256
#define NC 32
#define NCLS 10
#define KNN 10
#define KROWS 128
#define CTS 260
#define NPART 8

typedef float f32x4 __attribute__((ext_vector_type(4)));
typedef float f4v __attribute__((ext_vector_type(4)));
typedef short short8v __attribute__((ext_vector_type(8)));

__device__ __forceinline__ float wave_sum(float v) {
  #pragma unroll
  for (int off = 32; off; off >>= 1) v += __shfl_xor(v, off);
  return v;
}

__device__ __forceinline__ uint32_t fbits(float x) { return __builtin_bit_cast(uint32_t, x); }
__device__ __forceinline__ float bcast(uint32_t b) { return __builtin_bit_cast(float, b); }

// ============ k_key: 16x16x32 MFMA, split-K waves, ALL X-loads issued up-front ============
// 1024 thr / 16 waves / 128 rows. Wave w: rowgroup rg=w>>1 (rows rg*16..+15),
// k-half kh=w&1 (K-steps kh*4..kh*4+3). Only 8 f4 X-loads/thread (32 VGPR) ->
// hoisted up-front with NO spill; the Phase-A barrier drains vmcnt ONCE per block
// (amortized ~1 latency) instead of per-use. Partial acc combined via klb LDS
// (kh1 writes -2*acc + x2 in col 32; kh0 adds its part + x2 total).
__global__ __launch_bounds__(1024, 2) void k_key(const float* __restrict__ X,
                                                 const float* __restrict__ C,
                                                 float* __restrict__ candK,
                                                 int* __restrict__ candI,
                                                 int N, int G) {
  __shared__ uint4 shm[2048];            // 32 KB: [0,1024)=hi frags, [1024,2048)=lo
  int t = threadIdx.x;
  int lane = t & 63;
  int wvu = __builtin_amdgcn_readfirstlane(t >> 6);   // 0..15
  int rg = wvu >> 1, kh = wvu & 1;
  int rowbase = blockIdx.x * KROWS;

  int r16 = lane & 15, kg = lane >> 4;
  int grow = rowbase + rg * 16 + r16; if (grow >= N) grow = N - 1;
  const float* xp = X + (size_t)grow * D + kh * 128 + kg * 8;

  // --- Phase B FIRST: issue all 8 X-loads (stay in flight through Phase A) ---
  f4v xr[8];
  #pragma unroll
  for (int ksl = 0; ksl < 4; ++ksl) {
    xr[2 * ksl]     = __builtin_nontemporal_load(reinterpret_cast<const f4v*>(xp + ksl * 32));
    xr[2 * ksl + 1] = __builtin_nontemporal_load(reinterpret_cast<const f4v*>(xp + ksl * 32 + 4));
  }
  __builtin_amdgcn_sched_barrier(0);     // pin: do not sink loads

  // --- Phase A: self-compute bf16 hi/lo C fragments (one entry per thread) ---
  {
    int e = t;
    int q = e >> 6, l = e & 63;
    int tile = q >> 3, ksq = q & 7;
    int col = tile * 16 + (l & 15), kgf = (l >> 4) & 3;
    uint32_t h[8], lo[8];
    #pragma unroll
    for (int i = 0; i < 8; ++i) {
      int k = ksq * 32 + kgf * 8 + i;
      float x = C[(size_t)k * NC + col];
      uint32_t hb = fbits(x) & 0xFFFF0000u;
      h[i] = hb >> 16;
      lo[i] = fbits(x - bcast(hb)) >> 16;
    }
    shm[e] = make_uint4((h[1] << 16) | h[0], (h[3] << 16) | h[2],
                        (h[5] << 16) | h[4], (h[7] << 16) | h[6]);
    shm[1024 + e] = make_uint4((lo[1] << 16) | lo[0], (lo[3] << 16) | lo[2],
                               (lo[5] << 16) | lo[4], (lo[7] << 16) | lo[6]);
  }
  __syncthreads();   // one-time vmcnt drain for the whole block

  f32x4 aH0, aM0, aH1, aM1;
  #pragma unroll
  for (int i = 0; i < 4; ++i) { aH0[i] = 0.f; aM0[i] = 0.f; aH1[i] = 0.f; aM1[i] = 0.f; }
  float x2 = 0.f;

  // --- Phase C: 4 K-steps (this wave's k-half), pure reg+LDS, zero stalls ---
  #pragma unroll
  for (int ksl = 0; ksl < 4; ++ksl) {
    int ks = kh * 4 + ksl;
    f4v xa = xr[2 * ksl], xb = xr[2 * ksl + 1];
    float xs[8] = {xa[0], xa[1], xa[2], xa[3], xb[0], xb[1], xb[2], xb[3]};
    uint32_t hp[4], lp[4];
    #pragma unroll
    for (int p = 0; p < 4; ++p) {
      float x0 = xs[2 * p], x1 = xs[2 * p + 1];
      x2 = fmaf(x0, x0, x2); x2 = fmaf(x1, x1, x2);
      uint32_t h0 = fbits(x0) & 0xFFFF0000u, h1 = fbits(x1) & 0xFFFF0000u;
      hp[p] = h1 | (h0 >> 16);
      float r0 = x0 - bcast(h0), r1 = x1 - bcast(h1);
      lp[p] = (fbits(r1) & 0xFFFF0000u) | (fbits(r0) >> 16);
    }
    short8v xh = __builtin_bit_cast(short8v, make_uint4(hp[0], hp[1], hp[2], hp[3]));
    short8v xl = __builtin_bit_cast(short8v, make_uint4(lp[0], lp[1], lp[2], lp[3]));
    short8v b0h = __builtin_bit_cast(short8v, shm[ks * 64 + lane]);
    short8v b1h = __builtin_bit_cast(short8v, shm[(8 + ks) * 64 + lane]);
    short8v b0l = __builtin_bit_cast(short8v, shm[1024 + ks * 64 + lane]);
    short8v b1l = __builtin_bit_cast(short8v, shm[1024 + (8 + ks) * 64 + lane]);
    aH0 = __builtin_amdgcn_mfma_f32_16x16x32_bf16(xh, b0h, aH0, 0, 0, 0);
    aM0 = __builtin_amdgcn_mfma_f32_16x16x32_bf16(xh, b0l, aM0, 0, 0, 0);
    aM0 = __builtin_amdgcn_mfma_f32_16x16x32_bf16(xl, b0h, aM0, 0, 0, 0);
    aH1 = __builtin_amdgcn_mfma_f32_16x16x32_bf16(xh, b1h, aH1, 0, 0, 0);
    aM1 = __builtin_amdgcn_mfma_f32_16x16x32_bf16(xh, b1l, aM1, 0, 0, 0);
    aM1 = __builtin_amdgcn_mfma_f32_16x16x32_bf16(xl, b1h, aM1, 0, 0, 0);
  }

  x2 += __shfl_xor(x2, 16);
  x2 += __shfl_xor(x2, 32);          // lane l holds this k-half's x2 of row (l&15)

  __syncthreads();                    // all frag reads done -> alias shm
  float* klb = reinterpret_cast<float*>(shm);   // klb[row*33 + c], 128x33 (+col 32 = x2)

  if (kh == 1) {
    #pragma unroll
    for (int i = 0; i < 4; ++i) {
      int m = kg * 4 + i;                        // D-map (m89/m91)
      int rowl = rg * 16 + m;
      klb[rowl * 33 + r16]      = -2.f * (aH0[i] + aM0[i]);
      klb[rowl * 33 + 16 + r16] = -2.f * (aH1[i] + aM1[i]);
    }
    if (kg == 0) klb[(rg * 16 + r16) * 33 + 32] = x2;   // lane l=row
  }
  __syncthreads();
  if (kh == 0) {
    #pragma unroll
    for (int i = 0; i < 4; ++i) {
      int m = kg * 4 + i;
      int rowl = rg * 16 + m;
      float x2t = __shfl(x2, m) + klb[rowl * 33 + 32];   // both k-halves
      klb[rowl * 33 + r16]      += fmaf(-2.f, aH0[i] + aM0[i], x2t);
      klb[rowl * 33 + 16 + r16] += fmaf(-2.f, aH1[i] + aM1[i], x2t);
    }
  }
  __syncthreads();

  // --- block top-10 per concept (first 512 threads): team=16, 8 rows each ---
  if (t < 512) {
    int c = t >> 4, sub = t & 15;
    const float INF = 3.4e38f;
    float bk[8]; int bi[8];
    #pragma unroll
    for (int q = 0; q < 8; ++q) { bk[q] = INF; bi[q] = 0x7fffffff; }
    #pragma unroll
    for (int rr = 0; rr < 8; ++rr) {
      int rowl = sub * 8 + rr;
      int gi = rowbase + rowl;
      float v = (gi < N) ? klb[rowl * 33 + c] : INF;
      float cv = v; int ci = gi;
      #pragma unroll
      for (int q = 0; q < 8; ++q) {
        bool take = (cv < bk[q]) || (cv == bk[q] && ci < bi[q]);
        if (take) {
          float tf = bk[q]; bk[q] = cv; cv = tf;
          int ti = bi[q]; bi[q] = ci; ci = ti;
        }
      }
    }
    #pragma unroll
    for (int r = 0; r < KNN; ++r) {
      float mv = bk[0]; int mgi = bi[0];
      #pragma unroll
      for (int off = 1; off < 16; off <<= 1) {
        float ov = __shfl_xor(mv, off); int oi = __shfl_xor(mgi, off);
        if (ov < mv || (ov == mv && oi < mgi)) { mv = ov; mgi = oi; }
      }
      bool won = (bk[0] == mv) && (bi[0] == mgi);
      #pragma unroll
      for (int q = 0; q < 7; ++q) {
        bk[q] = won ? bk[q + 1] : bk[q];
        bi[q] = won ? bi[q + 1] : bi[q];
      }
      if (won) { bk[7] = INF; bi[7] = 0x7fffffff; }
      if (sub == 0) {
        candK[((size_t)c * G + blockIdx.x) * KNN + r] = mv;
        candI[((size_t)c * G + blockIdx.x) * KNN + r] = mgi;
      }
    }
  }
}

// ============ gram + GJ solve + stats + T2 = C*S + zero L1 slot ============
#define AUGW (NC + NCLS)   // 42
__global__ __launch_bounds__(1024) void k_gramsolve(const float* __restrict__ C,
                                                    const float* __restrict__ W,
                                                    float* __restrict__ T2,
                                                    float* __restrict__ out, int bs) {
  __shared__ float T[(NC + NCLS) * CTS];
  __shared__ float aug[NC * AUGW];
  __shared__ float Ssh[NC * NCLS];
  int tid = threadIdx.x;

  const float4* C4 = (const float4*)C;
  for (int s = tid; s < 2048; s += 1024) {
    float4 v = C4[s];
    int d = s >> 3, c0 = (s & 7) * 4;
    T[(c0 + 0) * CTS + d] = v.x; T[(c0 + 1) * CTS + d] = v.y;
    T[(c0 + 2) * CTS + d] = v.z; T[(c0 + 3) * CTS + d] = v.w;
  }
  const float2* W2 = (const float2*)W;
  for (int s = tid; s < 1280; s += 1024) {
    float2 v = W2[s];
    int d = s / 5, c0 = (s % 5) * 2;
    T[(NC + c0) * CTS + d] = v.x; T[(NC + c0 + 1) * CTS + d] = v.y;
  }
  __syncthreads();

  int lane = tid & 63, wv = tid >> 6;
  #pragma unroll
  for (int half = 0; half < 2; ++half) {
    int i = wv + half * 16;
    if (lane < AUGW) {
      const float4* ri = (const float4*)&T[i * CTS];
      const float4* rj = (const float4*)&T[lane * CTS];
      float acc = 0.f;
      #pragma unroll 8
      for (int d4 = 0; d4 < 64; ++d4) {
        float4 a = ri[d4], b = rj[d4];
        acc += a.x * b.x + a.y * b.y + a.z * b.z + a.w * b.w;
      }
      aug[i * AUGW + lane] = acc;
    }
  }
  __syncthreads();

  if (tid < NC) {
    int l2 = tid;
    float row[AUGW];
    #pragma unroll
    for (int c = 0; c < AUGW; ++c) row[c] = aug[l2 * AUGW + c];

    float rsum = 0.f;
    #pragma unroll
    for (int c = 0; c < NC; ++c) rsum += row[c];
    float diag = row[l2];
    #pragma unroll
    for (int off = 16; off; off >>= 1) {
      rsum += __shfl_xor(rsum, off);
      diag += __shfl_xor(diag, off);
    }
    if (l2 == 0) {
      out[(size_t)2 * bs * NCLS + 1] = (rsum - diag) / (float)(NC * NC);
      out[(size_t)2 * bs * NCLS + 2] = diag / (float)(NC * NC);
      out[(size_t)2 * bs * NCLS] = 0.f;      // L_sparse_1 accumulator (k_final2 adds)
    }

    for (int k = 0; k < NC; ++k) {
      float prow[AUGW];
      #pragma unroll
      for (int c = 0; c < AUGW; ++c) prow[c] = __shfl(row[c], k);
      float pinv = 1.0f / prow[k];
      float f = row[k] * pinv;
      if (l2 == k) {
        #pragma unroll
        for (int c = 0; c < AUGW; ++c) row[c] *= pinv;
      } else {
        #pragma unroll
        for (int c = 0; c < AUGW; ++c) row[c] -= f * prow[c];
      }
    }
    #pragma unroll
    for (int c = 0; c < NCLS; ++c) Ssh[l2 * NCLS + c] = row[NC + c];
  }
  __syncthreads();

  for (int e = tid; e < D * NCLS; e += 1024) {
    int d = e / NCLS, cls = e % NCLS;
    float acc = 0.f;
    #pragma unroll
    for (int c = 0; c < NC; ++c) acc += T[c * CTS + d] * Ssh[c * NCLS + cls];
    T2[e] = acc;
  }
}

// ============ predictions: orig_pred = Xb*W + b, y_pred = Xb*T2 + b ============
__global__ __launch_bounds__(256) void k_pred(const float* __restrict__ X,
                                              const float* __restrict__ W,
                                              const float* __restrict__ T2,
                                              const float* __restrict__ bvec,
                                              float* __restrict__ out, int bs) {
  __shared__ float2 Ws2[1280];
  __shared__ float2 Ts2[1280];
  int t = threadIdx.x;
  const float2* W2 = (const float2*)W;
  const float2* T22 = (const float2*)T2;
  for (int s = t; s < 1280; s += 256) { Ws2[s] = W2[s]; Ts2[s] = T22[s]; }
  __syncthreads();

  int r = blockIdx.x * 8 + (t >> 5);
  int q = t & 31;
  const float4* x4 = reinterpret_cast<const float4*>(X + (size_t)r * D);
  float4 xa = x4[q * 2], xb = x4[q * 2 + 1];

  float o[NCLS], y[NCLS];
  #pragma unroll
  for (int c = 0; c < NCLS; ++c) { o[c] = 0.f; y[c] = 0.f; }

  #pragma unroll
  for (int i = 0; i < 8; ++i) {
    int d = q * 8 + i;
    float xd = (i < 4) ? reinterpret_cast<const float*>(&xa)[i]
                       : reinterpret_cast<const float*>(&xb)[i - 4];
    #pragma unroll
    for (int j = 0; j < 5; ++j) {
      float2 wv = Ws2[d * 5 + j];
      float2 tv = Ts2[d * 5 + j];
      o[j * 2 + 0] += xd * wv.x; o[j * 2 + 1] += xd * wv.y;
      y[j * 2 + 0] += xd * tv.x; y[j * 2 + 1] += xd * tv.y;
    }
  }
  #pragma unroll
  for (int off = 1; off < 32; off <<= 1) {
    #pragma unroll
    for (int c = 0; c < NCLS; ++c) {
      o[c] += __shfl_xor(o[c], off);
      y[c] += __shfl_xor(y[c], off);
    }
  }
  if (q < NCLS) {
    float b = bvec[q];
    out[(size_t)r * NCLS + q] = o[q] + b;
    out[(size_t)bs * NCLS + (size_t)r * NCLS + q] = y[q] + b;
  }
}

// ============ shared block-merge helper (256 threads): local top-10 -> block top-10 ============
__device__ __forceinline__ void block_merge_top10(float* bk, int* bi, int tid,
                                                  float* sk, int* si,
                                                  float* wv_, int* wi_,
                                                  float* outK, int* outI) {
  const float INF = 3.4e38f;
  #pragma unroll
  for (int q = 0; q < KNN; ++q) { sk[tid * KNN + q] = bk[q]; si[tid * KNN + q] = bi[q]; }
  __syncthreads();
  int p = 0;
  int lane = tid & 63, wv = tid >> 6;
  for (int rr = 0; rr < KNN; ++rr) {
    float myv = (p < KNN) ? sk[tid * KNN + p] : INF;
    int mygi = (p < KNN) ? si[tid * KNN + p] : 0x7fffffff;
    float hv = myv; int hgi = mygi;
    #pragma unroll
    for (int off = 32; off; off >>= 1) {
      float ov = __shfl_xor(hv, off); int oi = __shfl_xor(hgi, off);
      if (ov < hv || (ov == hv && oi < hgi)) { hv = ov; hgi = oi; }
    }
    if (lane == 0) { wv_[wv] = hv; wi_[wv] = hgi; }
    __syncthreads();
    float bv = wv_[0]; int bgi = wi_[0];
    #pragma unroll
    for (int w = 1; w < 4; ++w) {
      if (wv_[w] < bv || (wv_[w] == bv && wi_[w] < bgi)) { bv = wv_[w]; bgi = wi_[w]; }
    }
    if (p < KNN && myv == bv && mygi == bgi) p++;
    if (tid == 0) { outK[rr] = bv; outI[rr] = bgi; }
    __syncthreads();
  }
}

// ============ k_fmerge: stage-1 merge, grid (NPART, NC) x 256 thr ============
__global__ __launch_bounds__(256) void k_fmerge(const float* __restrict__ candK,
                                                const int* __restrict__ candI,
                                                float* __restrict__ c2K,
                                                int* __restrict__ c2I, int G) {
  int j = blockIdx.y, part = blockIdx.x, tid = threadIdx.x;
  int M = G * KNN;
  int chunk = (M + NPART - 1) / NPART;
  int lo = part * chunk;
  int hi = lo + chunk; if (hi > M) hi = M;
  const float INF = 3.4e38f;

  float bk[KNN]; int bi[KNN];
  #pragma unroll
  for (int q = 0; q < KNN; ++q) { bk[q] = INF; bi[q] = 0x7fffffff; }
  for (int e = lo + tid; e < hi; e += 256) {
    float v = candK[(size_t)j * M + e];
    int gi = candI[(size_t)j * M + e];
    if (v < bk[KNN - 1] || (v == bk[KNN - 1] && gi < bi[KNN - 1])) {
      float cv = v; int ci = gi;
      #pragma unroll
      for (int q = 0; q < KNN; ++q) {
        bool take = (cv < bk[q]) || (cv == bk[q] && ci < bi[q]);
        if (take) {
          float tf = bk[q]; bk[q] = cv; cv = tf;
          int ti = bi[q]; bi[q] = ci; ci = ti;
        }
      }
    }
  }

  __shared__ float sk[256 * KNN];
  __shared__ int si[256 * KNN];
  __shared__ float wv_[4]; __shared__ int wi_[4];
  block_merge_top10(bk, bi, tid, sk, si, wv_, wi_,
                    c2K + ((size_t)j * NPART + part) * KNN,
                    c2I + ((size_t)j * NPART + part) * KNN);
}

// ============ k_final2: merge 80/concept + gather + dot + atomic sum ============
__global__ __launch_bounds__(256) void k_final2(const float* __restrict__ c2K,
                                                const int* __restrict__ c2I,
                                                const float* __restrict__ X,
                                                const float* __restrict__ Cc,
                                                float* __restrict__ out, int bs) {
  int j = blockIdx.x, tid = threadIdx.x;
  const int M2 = NPART * KNN;   // 80
  const float INF = 3.4e38f;

  float bk[KNN]; int bi[KNN];
  #pragma unroll
  for (int q = 0; q < KNN; ++q) { bk[q] = INF; bi[q] = 0x7fffffff; }
  if (tid < M2) {
    bk[0] = c2K[(size_t)j * M2 + tid];
    bi[0] = c2I[(size_t)j * M2 + tid];
  }

  __shared__ float sk[256 * KNN];
  __shared__ int si[256 * KNN];
  __shared__ float wv_[4]; __shared__ int wi_[4];
  __shared__ float topK[KNN]; __shared__ int topIdx[KNN];
  block_merge_top10(bk, bi, tid, sk, si, wv_, wi_, topK, topIdx);

  int lane = tid & 63, wv = tid >> 6;
  float cj = Cc[tid * NC + j];
  float acc = 0.f;
  #pragma unroll
  for (int k = 0; k < KNN; ++k) acc += X[(size_t)topIdx[k] * D + tid] * cj;
  acc = wave_sum(acc);
  __shared__ float rsum[4];
  if (lane == 0) rsum[wv] = acc;
  __syncthreads();
  if (tid == 0)
    atomicAdd(out + (size_t)2 * bs * NCLS,
              (rsum[0] + rsum[1] + rsum[2] + rsum[3]) * (1.0f / (KNN * NC)));
}

extern "C" void kernel_launch(void* const* d_in, const int* in_sizes, int n_in,
                              void* d_out, int out_size, void* d_ws, size_t ws_size,
                              hipStream_t stream) {
  const float* Xb = (const float*)d_in[0]; // train_embedding [bs][D]
  const float* XN = (const float*)d_in[1]; // train_embeddings [N][D]
  const float* C  = (const float*)d_in[2]; // concept [D][NC]
  const float* W  = (const float*)d_in[3]; // W_hx [D][NCLS]
  const float* bv = (const float*)d_in[4]; // b_hx [NCLS]
  float* out = (float*)d_out;

  int bs = in_sizes[0] / D;   // 4096
  int N  = in_sizes[1] / D;   // 200000
  int G  = (N + KROWS - 1) / KROWS;   // 1563

  float* w = (float*)d_ws;
  size_t offT2   = 0;                         // 2560 floats
  size_t offC2K  = 2560;                      // NC*NPART*KNN = 2560
  size_t offC2I  = offC2K + NC * NPART * KNN;
  size_t offCK   = offC2I + NC * NPART * KNN; // NC*G*KNN floats
  size_t offCI   = offCK + (size_t)NC * G * KNN;

  float* T2    = w + offT2;
  float* c2K   = w + offC2K;
  int*   c2I   = (int*)(w + offC2I);
  float* candK = w + offCK;
  int*   candI = (int*)(w + offCI);

  k_key<<<dim3(G), dim3(1024), 0, stream>>>(XN, C, candK, candI, N, G);
  k_gramsolve<<<dim3(1), dim3(1024), 0, stream>>>(C, W, T2, out, bs);
  k_pred<<<dim3(bs / 8), dim3(256), 0, stream>>>(Xb, W, T2, bv, out, bs);
  k_fmerge<<<dim3(NPART, NC), dim3(256), 0, stream>>>(candK, candI, c2K, c2I, G);
  k_final2<<<dim3(NC), dim3(256), 0, stream>>>(c2K, c2I, XN, C, out, bs);
}

// Round 22
// 169.102 us; speedup vs baseline: 1.1820x; 1.1820x over previous
//
#include <hip/hip_runtime.h>
#include <cstdint>

#define D 256
#define NC 32
#define NCLS 10
#define KNN 10
#define KROWS 128
#define NPART 8
#define PB 512   // pred blocks = bs/8

typedef float f32x4 __attribute__((ext_vector_type(4)));
typedef float f4v __attribute__((ext_vector_type(4)));
typedef short short8v __attribute__((ext_vector_type(8)));

__device__ __forceinline__ float wave_sum(float v) {
  #pragma unroll
  for (int off = 32; off; off >>= 1) v += __shfl_xor(v, off);
  return v;
}

__device__ __forceinline__ uint32_t fbits(float x) { return __builtin_bit_cast(uint32_t, x); }
__device__ __forceinline__ float bcast(uint32_t b) { return __builtin_bit_cast(float, b); }

#define AUGW (NC + NCLS)   // 42

// ============ k_main: blocks [0,G) = k_key (R20-verified form); block G = gram/solve/T2 ============
__global__ __launch_bounds__(512, 4) void k_main(const float* __restrict__ X,
                                                 const float* __restrict__ C,
                                                 const float* __restrict__ W,
                                                 float* __restrict__ candK,
                                                 int* __restrict__ candI,
                                                 float* __restrict__ T2,
                                                 float* __restrict__ out,
                                                 int N, int G, int bs) {
  __shared__ uint4 shm[2048];            // 32 KB (both paths)
  int t = threadIdx.x;

  if (blockIdx.x == (unsigned)G) {
    // ---------------- gram + GJ solve + stats + T2 path (1 block, hidden) ----------------
    float* Cf = reinterpret_cast<float*>(shm);      // 8192 floats
    {
      const float4* C4g = (const float4*)C;
      float4* Cf4 = (float4*)Cf;
      for (int s = t; s < 2048; s += 512) Cf4[s] = C4g[s];
    }
    __syncthreads();

    int lane = t & 63, wv8 = t >> 6;                // 8 waves
    float augv[4];
    #pragma unroll
    for (int h = 0; h < 4; ++h) {
      int i = wv8 + h * 8;
      float acc = 0.f;
      if (lane < AUGW) {
        for (int d = 0; d < D; ++d) {
          float ci = Cf[d * NC + i];                               // uniform -> bcast
          float bj = (lane < NC) ? Cf[d * NC + lane] : W[(size_t)d * NCLS + (lane - NC)];
          acc = fmaf(ci, bj, acc);
        }
      }
      augv[h] = acc;
    }
    __syncthreads();                                 // all C reads done
    float* augL = Cf;                                // reuse: 32*42 floats
    float* Ssh = Cf + 1400;                          // 320 floats
    #pragma unroll
    for (int h = 0; h < 4; ++h) {
      int i = wv8 + h * 8;
      if (lane < AUGW) augL[i * AUGW + lane] = augv[h];
    }
    __syncthreads();

    if (t < NC) {
      int l2 = t;
      float row[AUGW];
      #pragma unroll
      for (int c = 0; c < AUGW; ++c) row[c] = augL[l2 * AUGW + c];

      float rsum = 0.f;
      #pragma unroll
      for (int c = 0; c < NC; ++c) rsum += row[c];
      float diag = row[l2];
      #pragma unroll
      for (int off = 16; off; off >>= 1) {
        rsum += __shfl_xor(rsum, off);
        diag += __shfl_xor(diag, off);
      }
      if (l2 == 0) {
        out[(size_t)2 * bs * NCLS + 1] = (rsum - diag) / (float)(NC * NC);
        out[(size_t)2 * bs * NCLS + 2] = diag / (float)(NC * NC);
        out[(size_t)2 * bs * NCLS] = 0.f;            // L_sparse_1 acc (k_final2 adds)
      }

      for (int k = 0; k < NC; ++k) {
        float prow[AUGW];
        #pragma unroll
        for (int c = 0; c < AUGW; ++c) prow[c] = __shfl(row[c], k);
        float pinv = 1.0f / prow[k];
        float f = row[k] * pinv;
        if (l2 == k) {
          #pragma unroll
          for (int c = 0; c < AUGW; ++c) row[c] *= pinv;
        } else {
          #pragma unroll
          for (int c = 0; c < AUGW; ++c) row[c] -= f * prow[c];
        }
      }
      #pragma unroll
      for (int c = 0; c < NCLS; ++c) Ssh[l2 * NCLS + c] = row[NC + c];
    }
    __syncthreads();

    // T2[d][cls] = sum_c C[d][c] * S[c][cls]  (C re-read from global, L2-hot)
    for (int e = t; e < D * NCLS; e += 512) {
      int d = e / NCLS, cls = e % NCLS;
      float acc = 0.f;
      #pragma unroll
      for (int c = 0; c < NC; ++c) acc = fmaf(C[(size_t)d * NC + c], Ssh[c * NCLS + cls], acc);
      T2[e] = acc;
    }
    return;
  }

  // ---------------- k_key path (R20-verified) ----------------
  int lane = t & 63;
  int wvu = __builtin_amdgcn_readfirstlane(t >> 6);   // 0..7
  int rowbase = blockIdx.x * KROWS;

  #pragma unroll
  for (int e0 = 0; e0 < 1024; e0 += 512) {
    int e = e0 + t;
    int q = e >> 6, l = e & 63;
    int tile = q >> 3, ksq = q & 7;
    int col = tile * 16 + (l & 15), kg = (l >> 4) & 3;
    uint32_t h[8], lo[8];
    #pragma unroll
    for (int i = 0; i < 8; ++i) {
      int k = ksq * 32 + kg * 8 + i;
      float x = C[(size_t)k * NC + col];
      uint32_t hb = fbits(x) & 0xFFFF0000u;
      h[i] = hb >> 16;
      lo[i] = fbits(x - bcast(hb)) >> 16;
    }
    shm[e] = make_uint4((h[1] << 16) | h[0], (h[3] << 16) | h[2],
                        (h[5] << 16) | h[4], (h[7] << 16) | h[6]);
    shm[1024 + e] = make_uint4((lo[1] << 16) | lo[0], (lo[3] << 16) | lo[2],
                               (lo[5] << 16) | lo[4], (lo[7] << 16) | lo[6]);
  }
  __syncthreads();

  int r16 = lane & 15;
  int grow = rowbase + wvu * 16 + r16; if (grow >= N) grow = N - 1;
  const float* xp = X + (size_t)grow * D + ((lane >> 4) * 8);

  f32x4 aH0, aM0, aH1, aM1;
  #pragma unroll
  for (int i = 0; i < 4; ++i) { aH0[i] = 0.f; aM0[i] = 0.f; aH1[i] = 0.f; aM1[i] = 0.f; }
  float x2 = 0.f;

  #pragma unroll
  for (int ks = 0; ks < 8; ++ks) {
    f4v xa = __builtin_nontemporal_load(reinterpret_cast<const f4v*>(xp + ks * 32));
    f4v xb = __builtin_nontemporal_load(reinterpret_cast<const f4v*>(xp + ks * 32 + 4));
    float xs[8] = {xa[0], xa[1], xa[2], xa[3], xb[0], xb[1], xb[2], xb[3]};
    uint32_t hp[4], lp[4];
    #pragma unroll
    for (int p = 0; p < 4; ++p) {
      float x0 = xs[2 * p], x1 = xs[2 * p + 1];
      x2 = fmaf(x0, x0, x2); x2 = fmaf(x1, x1, x2);
      uint32_t h0 = fbits(x0) & 0xFFFF0000u, h1 = fbits(x1) & 0xFFFF0000u;
      hp[p] = h1 | (h0 >> 16);
      float r0 = x0 - bcast(h0), r1 = x1 - bcast(h1);
      lp[p] = (fbits(r1) & 0xFFFF0000u) | (fbits(r0) >> 16);
    }
    short8v xh = __builtin_bit_cast(short8v, make_uint4(hp[0], hp[1], hp[2], hp[3]));
    short8v xl = __builtin_bit_cast(short8v, make_uint4(lp[0], lp[1], lp[2], lp[3]));
    short8v b0h = __builtin_bit_cast(short8v, shm[ks * 64 + lane]);
    short8v b1h = __builtin_bit_cast(short8v, shm[(8 + ks) * 64 + lane]);
    short8v b0l = __builtin_bit_cast(short8v, shm[1024 + ks * 64 + lane]);
    short8v b1l = __builtin_bit_cast(short8v, shm[1024 + (8 + ks) * 64 + lane]);
    aH0 = __builtin_amdgcn_mfma_f32_16x16x32_bf16(xh, b0h, aH0, 0, 0, 0);
    aM0 = __builtin_amdgcn_mfma_f32_16x16x32_bf16(xh, b0l, aM0, 0, 0, 0);
    aM0 = __builtin_amdgcn_mfma_f32_16x16x32_bf16(xl, b0h, aM0, 0, 0, 0);
    aH1 = __builtin_amdgcn_mfma_f32_16x16x32_bf16(xh, b1h, aH1, 0, 0, 0);
    aM1 = __builtin_amdgcn_mfma_f32_16x16x32_bf16(xh, b1l, aM1, 0, 0, 0);
    aM1 = __builtin_amdgcn_mfma_f32_16x16x32_bf16(xl, b1h, aM1, 0, 0, 0);
  }

  x2 += __shfl_xor(x2, 16);
  x2 += __shfl_xor(x2, 32);          // lane l holds x2 of row (l&15)

  __syncthreads();
  float* klb = reinterpret_cast<float*>(shm);   // klb[row*33 + c], 128x33
  #pragma unroll
  for (int i = 0; i < 4; ++i) {
    int m = (lane >> 4) * 4 + i;                 // X-row within wave tile (m89/m91)
    float x2m = __shfl(x2, m);
    int rowl = wvu * 16 + m;
    klb[rowl * 33 + r16]      = fmaf(-2.f, aH0[i] + aM0[i], x2m);
    klb[rowl * 33 + 16 + r16] = fmaf(-2.f, aH1[i] + aM1[i], x2m);
  }
  __syncthreads();

  {
    int c = t >> 4, sub = t & 15;
    const float INF = 3.4e38f;
    float bk[8]; int bi[8];
    #pragma unroll
    for (int q = 0; q < 8; ++q) { bk[q] = INF; bi[q] = 0x7fffffff; }
    #pragma unroll
    for (int rr = 0; rr < 8; ++rr) {
      int rowl = sub * 8 + rr;
      int gi = rowbase + rowl;
      float v = (gi < N) ? klb[rowl * 33 + c] : INF;
      float cv = v; int ci = gi;
      #pragma unroll
      for (int q = 0; q < 8; ++q) {
        bool take = (cv < bk[q]) || (cv == bk[q] && ci < bi[q]);
        if (take) {
          float tf = bk[q]; bk[q] = cv; cv = tf;
          int ti = bi[q]; bi[q] = ci; ci = ti;
        }
      }
    }
    #pragma unroll
    for (int r = 0; r < KNN; ++r) {
      float mv = bk[0]; int mgi = bi[0];
      #pragma unroll
      for (int off = 1; off < 16; off <<= 1) {
        float ov = __shfl_xor(mv, off); int oi = __shfl_xor(mgi, off);
        if (ov < mv || (ov == mv && oi < mgi)) { mv = ov; mgi = oi; }
      }
      bool won = (bk[0] == mv) && (bi[0] == mgi);
      #pragma unroll
      for (int q = 0; q < 7; ++q) {
        bk[q] = won ? bk[q + 1] : bk[q];
        bi[q] = won ? bi[q + 1] : bi[q];
      }
      if (won) { bk[7] = INF; bi[7] = 0x7fffffff; }
      if (sub == 0) {
        candK[((size_t)c * G + blockIdx.x) * KNN + r] = mv;
        candI[((size_t)c * G + blockIdx.x) * KNN + r] = mgi;
      }
    }
  }
}

// ============ shared block-merge helper (256 threads) ============
__device__ __forceinline__ void block_merge_top10(float* bk, int* bi, int tid,
                                                  float* sk, int* si,
                                                  float* wv_, int* wi_,
                                                  float* outK, int* outI) {
  const float INF = 3.4e38f;
  #pragma unroll
  for (int q = 0; q < KNN; ++q) { sk[tid * KNN + q] = bk[q]; si[tid * KNN + q] = bi[q]; }
  __syncthreads();
  int p = 0;
  int lane = tid & 63, wv = tid >> 6;
  for (int rr = 0; rr < KNN; ++rr) {
    float myv = (p < KNN) ? sk[tid * KNN + p] : INF;
    int mygi = (p < KNN) ? si[tid * KNN + p] : 0x7fffffff;
    float hv = myv; int hgi = mygi;
    #pragma unroll
    for (int off = 32; off; off >>= 1) {
      float ov = __shfl_xor(hv, off); int oi = __shfl_xor(hgi, off);
      if (ov < hv || (ov == hv && oi < hgi)) { hv = ov; hgi = oi; }
    }
    if (lane == 0) { wv_[wv] = hv; wi_[wv] = hgi; }
    __syncthreads();
    float bv = wv_[0]; int bgi = wi_[0];
    #pragma unroll
    for (int w = 1; w < 4; ++w) {
      if (wv_[w] < bv || (wv_[w] == bv && wi_[w] < bgi)) { bv = wv_[w]; bgi = wi_[w]; }
    }
    if (p < KNN && myv == bv && mygi == bgi) p++;
    if (tid == 0) { outK[rr] = bv; outI[rr] = bgi; }
    __syncthreads();
  }
}

// ============ k_pf: blocks [0,PB) = pred; blocks [PB, PB+NPART*NC) = fmerge ============
__global__ __launch_bounds__(256) void k_pf(const float* __restrict__ Xb,
                                            const float* __restrict__ W,
                                            const float* __restrict__ T2,
                                            const float* __restrict__ bvec,
                                            float* __restrict__ out,
                                            const float* __restrict__ candK,
                                            const int* __restrict__ candI,
                                            float* __restrict__ c2K,
                                            int* __restrict__ c2I, int G, int bs) {
  __shared__ __align__(16) char smem[20800];
  int t = threadIdx.x;

  if (blockIdx.x < (unsigned)PB) {
    // ---------------- pred path ----------------
    float2* Ws2 = (float2*)smem;                 // 1280 float2 = 10240 B
    float2* Ts2 = (float2*)(smem + 10240);       // 1280 float2
    const float2* W2 = (const float2*)W;
    const float2* T22 = (const float2*)T2;
    for (int s = t; s < 1280; s += 256) { Ws2[s] = W2[s]; Ts2[s] = T22[s]; }
    __syncthreads();

    int r = blockIdx.x * 8 + (t >> 5);
    int q = t & 31;
    const float4* x4 = reinterpret_cast<const float4*>(Xb + (size_t)r * D);
    float4 xa = x4[q * 2], xb = x4[q * 2 + 1];

    float o[NCLS], y[NCLS];
    #pragma unroll
    for (int c = 0; c < NCLS; ++c) { o[c] = 0.f; y[c] = 0.f; }

    #pragma unroll
    for (int i = 0; i < 8; ++i) {
      int d = q * 8 + i;
      float xd = (i < 4) ? reinterpret_cast<const float*>(&xa)[i]
                         : reinterpret_cast<const float*>(&xb)[i - 4];
      #pragma unroll
      for (int j = 0; j < 5; ++j) {
        float2 wv = Ws2[d * 5 + j];
        float2 tv = Ts2[d * 5 + j];
        o[j * 2 + 0] += xd * wv.x; o[j * 2 + 1] += xd * wv.y;
        y[j * 2 + 0] += xd * tv.x; y[j * 2 + 1] += xd * tv.y;
      }
    }
    #pragma unroll
    for (int off = 1; off < 32; off <<= 1) {
      #pragma unroll
      for (int c = 0; c < NCLS; ++c) {
        o[c] += __shfl_xor(o[c], off);
        y[c] += __shfl_xor(y[c], off);
      }
    }
    if (q < NCLS) {
      float b = bvec[q];
      out[(size_t)r * NCLS + q] = o[q] + b;
      out[(size_t)bs * NCLS + (size_t)r * NCLS + q] = y[q] + b;
    }
    return;
  }

  // ---------------- fmerge path ----------------
  int bid = blockIdx.x - PB;
  int part = bid % NPART, j = bid / NPART;
  int M = G * KNN;
  int chunk = (M + NPART - 1) / NPART;
  int lo = part * chunk;
  int hi = lo + chunk; if (hi > M) hi = M;
  const float INF = 3.4e38f;

  float bk[KNN]; int bi[KNN];
  #pragma unroll
  for (int q = 0; q < KNN; ++q) { bk[q] = INF; bi[q] = 0x7fffffff; }
  for (int e = lo + t; e < hi; e += 256) {
    float v = candK[(size_t)j * M + e];
    int gi = candI[(size_t)j * M + e];
    if (v < bk[KNN - 1] || (v == bk[KNN - 1] && gi < bi[KNN - 1])) {
      float cv = v; int ci = gi;
      #pragma unroll
      for (int q = 0; q < KNN; ++q) {
        bool take = (cv < bk[q]) || (cv == bk[q] && ci < bi[q]);
        if (take) {
          float tf = bk[q]; bk[q] = cv; cv = tf;
          int ti = bi[q]; bi[q] = ci; ci = ti;
        }
      }
    }
  }

  float* sk = (float*)smem;                    // 2560 floats
  int* si = (int*)(smem + 10240);              // 2560 ints
  float* wv_ = (float*)(smem + 20480);
  int* wi_ = (int*)(smem + 20480 + 16);
  block_merge_top10(bk, bi, t, sk, si, wv_, wi_,
                    c2K + ((size_t)j * NPART + part) * KNN,
                    c2I + ((size_t)j * NPART + part) * KNN);
}

// ============ k_final2: merge 80/concept + gather + dot + atomic sum ============
__global__ __launch_bounds__(256) void k_final2(const float* __restrict__ c2K,
                                                const int* __restrict__ c2I,
                                                const float* __restrict__ X,
                                                const float* __restrict__ Cc,
                                                float* __restrict__ out, int bs) {
  int j = blockIdx.x, tid = threadIdx.x;
  const int M2 = NPART * KNN;   // 80
  const float INF = 3.4e38f;

  float bk[KNN]; int bi[KNN];
  #pragma unroll
  for (int q = 0; q < KNN; ++q) { bk[q] = INF; bi[q] = 0x7fffffff; }
  if (tid < M2) {
    bk[0] = c2K[(size_t)j * M2 + tid];
    bi[0] = c2I[(size_t)j * M2 + tid];
  }

  __shared__ float sk[256 * KNN];
  __shared__ int si[256 * KNN];
  __shared__ float wv_[4]; __shared__ int wi_[4];
  __shared__ float topK[KNN]; __shared__ int topIdx[KNN];
  block_merge_top10(bk, bi, tid, sk, si, wv_, wi_, topK, topIdx);

  int lane = tid & 63, wv = tid >> 6;
  float cj = Cc[tid * NC + j];
  float acc = 0.f;
  #pragma unroll
  for (int k = 0; k < KNN; ++k) acc += X[(size_t)topIdx[k] * D + tid] * cj;
  acc = wave_sum(acc);
  __shared__ float rsum[4];
  if (lane == 0) rsum[wv] = acc;
  __syncthreads();
  if (tid == 0)
    atomicAdd(out + (size_t)2 * bs * NCLS,
              (rsum[0] + rsum[1] + rsum[2] + rsum[3]) * (1.0f / (KNN * NC)));
}

extern "C" void kernel_launch(void* const* d_in, const int* in_sizes, int n_in,
                              void* d_out, int out_size, void* d_ws, size_t ws_size,
                              hipStream_t stream) {
  const float* Xb = (const float*)d_in[0]; // train_embedding [bs][D]
  const float* XN = (const float*)d_in[1]; // train_embeddings [N][D]
  const float* C  = (const float*)d_in[2]; // concept [D][NC]
  const float* W  = (const float*)d_in[3]; // W_hx [D][NCLS]
  const float* bv = (const float*)d_in[4]; // b_hx [NCLS]
  float* out = (float*)d_out;

  int bs = in_sizes[0] / D;   // 4096
  int N  = in_sizes[1] / D;   // 200000
  int G  = (N + KROWS - 1) / KROWS;   // 1563

  float* w = (float*)d_ws;
  size_t offT2   = 0;                         // 2560 floats
  size_t offC2K  = 2560;                      // NC*NPART*KNN = 2560
  size_t offC2I  = offC2K + NC * NPART * KNN;
  size_t offCK   = offC2I + NC * NPART * KNN; // NC*G*KNN floats
  size_t offCI   = offCK + (size_t)NC * G * KNN;

  float* T2    = w + offT2;
  float* c2K   = w + offC2K;
  int*   c2I   = (int*)(w + offC2I);
  float* candK = w + offCK;
  int*   candI = (int*)(w + offCI);

  k_main<<<dim3(G + 1), dim3(512), 0, stream>>>(XN, C, W, candK, candI, T2, out, N, G, bs);
  k_pf<<<dim3(PB + NPART * NC), dim3(256), 0, stream>>>(Xb, W, T2, bv, out,
                                                        candK, candI, c2K, c2I, G, bs);
  k_final2<<<dim3(NC), dim3(256), 0, stream>>>(c2K, c2I, XN, C, out, bs);
}

// Round 23
// 140.383 us; speedup vs baseline: 1.4238x; 1.2046x over previous
//
#include <hip/hip_runtime.h>
#include <cstdint>

#define D 256
#define NC 32
#define NCLS 10
#define KNN 10
#define KROWS 128
#define CTS 260
#define NPART 8
#define PB 512   // pred blocks = bs/8

typedef float f32x4 __attribute__((ext_vector_type(4)));
typedef float f4v __attribute__((ext_vector_type(4)));
typedef short short8v __attribute__((ext_vector_type(8)));

__device__ __forceinline__ float wave_sum(float v) {
  #pragma unroll
  for (int off = 32; off; off >>= 1) v += __shfl_xor(v, off);
  return v;
}

__device__ __forceinline__ uint32_t fbits(float x) { return __builtin_bit_cast(uint32_t, x); }
__device__ __forceinline__ float bcast(uint32_t b) { return __builtin_bit_cast(float, b); }

// ============ k_key: 16x16x32 MFMA, X direct (nontemporal), self C-frags ============
// (R20-verified form: best measured config — DO NOT co-compile with cold paths)
__global__ __launch_bounds__(512, 4) void k_key(const float* __restrict__ X,
                                                const float* __restrict__ C,
                                                float* __restrict__ candK,
                                                int* __restrict__ candI,
                                                int N, int G) {
  __shared__ uint4 shm[2048];            // 32 KB: [0,1024)=hi frags, [1024,2048)=lo
  int t = threadIdx.x;
  int lane = t & 63;
  int wvu = __builtin_amdgcn_readfirstlane(t >> 6);   // 0..7
  int rowbase = blockIdx.x * KROWS;

  #pragma unroll
  for (int e0 = 0; e0 < 1024; e0 += 512) {
    int e = e0 + t;
    int q = e >> 6, l = e & 63;
    int tile = q >> 3, ksq = q & 7;
    int col = tile * 16 + (l & 15), kg = (l >> 4) & 3;
    uint32_t h[8], lo[8];
    #pragma unroll
    for (int i = 0; i < 8; ++i) {
      int k = ksq * 32 + kg * 8 + i;
      float x = C[(size_t)k * NC + col];
      uint32_t hb = fbits(x) & 0xFFFF0000u;
      h[i] = hb >> 16;
      lo[i] = fbits(x - bcast(hb)) >> 16;
    }
    shm[e] = make_uint4((h[1] << 16) | h[0], (h[3] << 16) | h[2],
                        (h[5] << 16) | h[4], (h[7] << 16) | h[6]);
    shm[1024 + e] = make_uint4((lo[1] << 16) | lo[0], (lo[3] << 16) | lo[2],
                               (lo[5] << 16) | lo[4], (lo[7] << 16) | lo[6]);
  }
  __syncthreads();

  int r16 = lane & 15;
  int grow = rowbase + wvu * 16 + r16; if (grow >= N) grow = N - 1;
  const float* xp = X + (size_t)grow * D + ((lane >> 4) * 8);

  f32x4 aH0, aM0, aH1, aM1;
  #pragma unroll
  for (int i = 0; i < 4; ++i) { aH0[i] = 0.f; aM0[i] = 0.f; aH1[i] = 0.f; aM1[i] = 0.f; }
  float x2 = 0.f;

  #pragma unroll
  for (int ks = 0; ks < 8; ++ks) {
    f4v xa = __builtin_nontemporal_load(reinterpret_cast<const f4v*>(xp + ks * 32));
    f4v xb = __builtin_nontemporal_load(reinterpret_cast<const f4v*>(xp + ks * 32 + 4));
    float xs[8] = {xa[0], xa[1], xa[2], xa[3], xb[0], xb[1], xb[2], xb[3]};
    uint32_t hp[4], lp[4];
    #pragma unroll
    for (int p = 0; p < 4; ++p) {
      float x0 = xs[2 * p], x1 = xs[2 * p + 1];
      x2 = fmaf(x0, x0, x2); x2 = fmaf(x1, x1, x2);
      uint32_t h0 = fbits(x0) & 0xFFFF0000u, h1 = fbits(x1) & 0xFFFF0000u;
      hp[p] = h1 | (h0 >> 16);
      float r0 = x0 - bcast(h0), r1 = x1 - bcast(h1);
      lp[p] = (fbits(r1) & 0xFFFF0000u) | (fbits(r0) >> 16);
    }
    short8v xh = __builtin_bit_cast(short8v, make_uint4(hp[0], hp[1], hp[2], hp[3]));
    short8v xl = __builtin_bit_cast(short8v, make_uint4(lp[0], lp[1], lp[2], lp[3]));
    short8v b0h = __builtin_bit_cast(short8v, shm[ks * 64 + lane]);
    short8v b1h = __builtin_bit_cast(short8v, shm[(8 + ks) * 64 + lane]);
    short8v b0l = __builtin_bit_cast(short8v, shm[1024 + ks * 64 + lane]);
    short8v b1l = __builtin_bit_cast(short8v, shm[1024 + (8 + ks) * 64 + lane]);
    aH0 = __builtin_amdgcn_mfma_f32_16x16x32_bf16(xh, b0h, aH0, 0, 0, 0);
    aM0 = __builtin_amdgcn_mfma_f32_16x16x32_bf16(xh, b0l, aM0, 0, 0, 0);
    aM0 = __builtin_amdgcn_mfma_f32_16x16x32_bf16(xl, b0h, aM0, 0, 0, 0);
    aH1 = __builtin_amdgcn_mfma_f32_16x16x32_bf16(xh, b1h, aH1, 0, 0, 0);
    aM1 = __builtin_amdgcn_mfma_f32_16x16x32_bf16(xh, b1l, aM1, 0, 0, 0);
    aM1 = __builtin_amdgcn_mfma_f32_16x16x32_bf16(xl, b1h, aM1, 0, 0, 0);
  }

  x2 += __shfl_xor(x2, 16);
  x2 += __shfl_xor(x2, 32);          // lane l holds x2 of row (l&15)

  __syncthreads();
  float* klb = reinterpret_cast<float*>(shm);   // klb[row*33 + c], 128x33
  #pragma unroll
  for (int i = 0; i < 4; ++i) {
    int m = (lane >> 4) * 4 + i;                 // X-row within wave tile (m89/m91)
    float x2m = __shfl(x2, m);
    int rowl = wvu * 16 + m;
    klb[rowl * 33 + r16]      = fmaf(-2.f, aH0[i] + aM0[i], x2m);
    klb[rowl * 33 + 16 + r16] = fmaf(-2.f, aH1[i] + aM1[i], x2m);
  }
  __syncthreads();

  // block top-10 per concept: team = 16 threads, c = t>>4, sub = t&15, 8 rows each
  {
    int c = t >> 4, sub = t & 15;
    const float INF = 3.4e38f;
    float bk[8]; int bi[8];
    #pragma unroll
    for (int q = 0; q < 8; ++q) { bk[q] = INF; bi[q] = 0x7fffffff; }
    #pragma unroll
    for (int rr = 0; rr < 8; ++rr) {
      int rowl = sub * 8 + rr;
      int gi = rowbase + rowl;
      float v = (gi < N) ? klb[rowl * 33 + c] : INF;
      float cv = v; int ci = gi;
      #pragma unroll
      for (int q = 0; q < 8; ++q) {
        bool take = (cv < bk[q]) || (cv == bk[q] && ci < bi[q]);
        if (take) {
          float tf = bk[q]; bk[q] = cv; cv = tf;
          int ti = bi[q]; bi[q] = ci; ci = ti;
        }
      }
    }
    #pragma unroll
    for (int r = 0; r < KNN; ++r) {
      float mv = bk[0]; int mgi = bi[0];
      #pragma unroll
      for (int off = 1; off < 16; off <<= 1) {
        float ov = __shfl_xor(mv, off); int oi = __shfl_xor(mgi, off);
        if (ov < mv || (ov == mv && oi < mgi)) { mv = ov; mgi = oi; }
      }
      bool won = (bk[0] == mv) && (bi[0] == mgi);
      #pragma unroll
      for (int q = 0; q < 7; ++q) {
        bk[q] = won ? bk[q + 1] : bk[q];
        bi[q] = won ? bi[q + 1] : bi[q];
      }
      if (won) { bk[7] = INF; bi[7] = 0x7fffffff; }
      if (sub == 0) {
        candK[((size_t)c * G + blockIdx.x) * KNN + r] = mv;
        candI[((size_t)c * G + blockIdx.x) * KNN + r] = mgi;
      }
    }
  }
}

// ============ gram + GJ solve + stats + T2 = C*S + zero L1 slot (R20 form) ============
#define AUGW (NC + NCLS)   // 42
__global__ __launch_bounds__(1024) void k_gramsolve(const float* __restrict__ C,
                                                    const float* __restrict__ W,
                                                    float* __restrict__ T2,
                                                    float* __restrict__ out, int bs) {
  __shared__ float T[(NC + NCLS) * CTS];
  __shared__ float aug[NC * AUGW];
  __shared__ float Ssh[NC * NCLS];
  int tid = threadIdx.x;

  const float4* C4 = (const float4*)C;
  for (int s = tid; s < 2048; s += 1024) {
    float4 v = C4[s];
    int d = s >> 3, c0 = (s & 7) * 4;
    T[(c0 + 0) * CTS + d] = v.x; T[(c0 + 1) * CTS + d] = v.y;
    T[(c0 + 2) * CTS + d] = v.z; T[(c0 + 3) * CTS + d] = v.w;
  }
  const float2* W2 = (const float2*)W;
  for (int s = tid; s < 1280; s += 1024) {
    float2 v = W2[s];
    int d = s / 5, c0 = (s % 5) * 2;
    T[(NC + c0) * CTS + d] = v.x; T[(NC + c0 + 1) * CTS + d] = v.y;
  }
  __syncthreads();

  int lane = tid & 63, wv = tid >> 6;
  #pragma unroll
  for (int half = 0; half < 2; ++half) {
    int i = wv + half * 16;
    if (lane < AUGW) {
      const float4* ri = (const float4*)&T[i * CTS];
      const float4* rj = (const float4*)&T[lane * CTS];
      float acc = 0.f;
      #pragma unroll 8
      for (int d4 = 0; d4 < 64; ++d4) {
        float4 a = ri[d4], b = rj[d4];
        acc += a.x * b.x + a.y * b.y + a.z * b.z + a.w * b.w;
      }
      aug[i * AUGW + lane] = acc;
    }
  }
  __syncthreads();

  if (tid < NC) {
    int l2 = tid;
    float row[AUGW];
    #pragma unroll
    for (int c = 0; c < AUGW; ++c) row[c] = aug[l2 * AUGW + c];

    float rsum = 0.f;
    #pragma unroll
    for (int c = 0; c < NC; ++c) rsum += row[c];
    float diag = row[l2];
    #pragma unroll
    for (int off = 16; off; off >>= 1) {
      rsum += __shfl_xor(rsum, off);
      diag += __shfl_xor(diag, off);
    }
    if (l2 == 0) {
      out[(size_t)2 * bs * NCLS + 1] = (rsum - diag) / (float)(NC * NC);
      out[(size_t)2 * bs * NCLS + 2] = diag / (float)(NC * NC);
      out[(size_t)2 * bs * NCLS] = 0.f;      // L_sparse_1 accumulator (k_final2 adds)
    }

    for (int k = 0; k < NC; ++k) {
      float prow[AUGW];
      #pragma unroll
      for (int c = 0; c < AUGW; ++c) prow[c] = __shfl(row[c], k);
      float pinv = 1.0f / prow[k];
      float f = row[k] * pinv;
      if (l2 == k) {
        #pragma unroll
        for (int c = 0; c < AUGW; ++c) row[c] *= pinv;
      } else {
        #pragma unroll
        for (int c = 0; c < AUGW; ++c) row[c] -= f * prow[c];
      }
    }
    #pragma unroll
    for (int c = 0; c < NCLS; ++c) Ssh[l2 * NCLS + c] = row[NC + c];
  }
  __syncthreads();

  for (int e = tid; e < D * NCLS; e += 1024) {
    int d = e / NCLS, cls = e % NCLS;
    float acc = 0.f;
    #pragma unroll
    for (int c = 0; c < NC; ++c) acc += T[c * CTS + d] * Ssh[c * NCLS + cls];
    T2[e] = acc;
  }
}

// ============ shared block-merge helper (256 threads) ============
__device__ __forceinline__ void block_merge_top10(float* bk, int* bi, int tid,
                                                  float* sk, int* si,
                                                  float* wv_, int* wi_,
                                                  float* outK, int* outI) {
  const float INF = 3.4e38f;
  #pragma unroll
  for (int q = 0; q < KNN; ++q) { sk[tid * KNN + q] = bk[q]; si[tid * KNN + q] = bi[q]; }
  __syncthreads();
  int p = 0;
  int lane = tid & 63, wv = tid >> 6;
  for (int rr = 0; rr < KNN; ++rr) {
    float myv = (p < KNN) ? sk[tid * KNN + p] : INF;
    int mygi = (p < KNN) ? si[tid * KNN + p] : 0x7fffffff;
    float hv = myv; int hgi = mygi;
    #pragma unroll
    for (int off = 32; off; off >>= 1) {
      float ov = __shfl_xor(hv, off); int oi = __shfl_xor(hgi, off);
      if (ov < hv || (ov == hv && oi < hgi)) { hv = ov; hgi = oi; }
    }
    if (lane == 0) { wv_[wv] = hv; wi_[wv] = hgi; }
    __syncthreads();
    float bv = wv_[0]; int bgi = wi_[0];
    #pragma unroll
    for (int w = 1; w < 4; ++w) {
      if (wv_[w] < bv || (wv_[w] == bv && wi_[w] < bgi)) { bv = wv_[w]; bgi = wi_[w]; }
    }
    if (p < KNN && myv == bv && mygi == bgi) p++;
    if (tid == 0) { outK[rr] = bv; outI[rr] = bgi; }
    __syncthreads();
  }
}

// ============ k_pf: blocks [0,PB) = pred; blocks [PB, PB+NPART*NC) = fmerge ============
// Both paths are cold/small; fusing them shares no state with the hot k_key kernel.
__global__ __launch_bounds__(256) void k_pf(const float* __restrict__ Xb,
                                            const float* __restrict__ W,
                                            const float* __restrict__ T2,
                                            const float* __restrict__ bvec,
                                            float* __restrict__ out,
                                            const float* __restrict__ candK,
                                            const int* __restrict__ candI,
                                            float* __restrict__ c2K,
                                            int* __restrict__ c2I, int G, int bs) {
  __shared__ __align__(16) char smem[20800];
  int t = threadIdx.x;

  if (blockIdx.x < (unsigned)PB) {
    // ---------------- pred path ----------------
    float2* Ws2 = (float2*)smem;                 // 1280 float2 = 10240 B
    float2* Ts2 = (float2*)(smem + 10240);       // 1280 float2
    const float2* W2 = (const float2*)W;
    const float2* T22 = (const float2*)T2;
    for (int s = t; s < 1280; s += 256) { Ws2[s] = W2[s]; Ts2[s] = T22[s]; }
    __syncthreads();

    int r = blockIdx.x * 8 + (t >> 5);
    int q = t & 31;
    const float4* x4 = reinterpret_cast<const float4*>(Xb + (size_t)r * D);
    float4 xa = x4[q * 2], xb = x4[q * 2 + 1];

    float o[NCLS], y[NCLS];
    #pragma unroll
    for (int c = 0; c < NCLS; ++c) { o[c] = 0.f; y[c] = 0.f; }

    #pragma unroll
    for (int i = 0; i < 8; ++i) {
      int d = q * 8 + i;
      float xd = (i < 4) ? reinterpret_cast<const float*>(&xa)[i]
                         : reinterpret_cast<const float*>(&xb)[i - 4];
      #pragma unroll
      for (int j = 0; j < 5; ++j) {
        float2 wv = Ws2[d * 5 + j];
        float2 tv = Ts2[d * 5 + j];
        o[j * 2 + 0] += xd * wv.x; o[j * 2 + 1] += xd * wv.y;
        y[j * 2 + 0] += xd * tv.x; y[j * 2 + 1] += xd * tv.y;
      }
    }
    #pragma unroll
    for (int off = 1; off < 32; off <<= 1) {
      #pragma unroll
      for (int c = 0; c < NCLS; ++c) {
        o[c] += __shfl_xor(o[c], off);
        y[c] += __shfl_xor(y[c], off);
      }
    }
    if (q < NCLS) {
      float b = bvec[q];
      out[(size_t)r * NCLS + q] = o[q] + b;
      out[(size_t)bs * NCLS + (size_t)r * NCLS + q] = y[q] + b;
    }
    return;
  }

  // ---------------- fmerge path ----------------
  int bid = blockIdx.x - PB;
  int part = bid % NPART, j = bid / NPART;
  int M = G * KNN;
  int chunk = (M + NPART - 1) / NPART;
  int lo = part * chunk;
  int hi = lo + chunk; if (hi > M) hi = M;
  const float INF = 3.4e38f;

  float bk[KNN]; int bi[KNN];
  #pragma unroll
  for (int q = 0; q < KNN; ++q) { bk[q] = INF; bi[q] = 0x7fffffff; }
  for (int e = lo + t; e < hi; e += 256) {
    float v = candK[(size_t)j * M + e];
    int gi = candI[(size_t)j * M + e];
    if (v < bk[KNN - 1] || (v == bk[KNN - 1] && gi < bi[KNN - 1])) {
      float cv = v; int ci = gi;
      #pragma unroll
      for (int q = 0; q < KNN; ++q) {
        bool take = (cv < bk[q]) || (cv == bk[q] && ci < bi[q]);
        if (take) {
          float tf = bk[q]; bk[q] = cv; cv = tf;
          int ti = bi[q]; bi[q] = ci; ci = ti;
        }
      }
    }
  }

  float* sk = (float*)smem;                    // 2560 floats
  int* si = (int*)(smem + 10240);              // 2560 ints
  float* wv_ = (float*)(smem + 20480);
  int* wi_ = (int*)(smem + 20480 + 16);
  block_merge_top10(bk, bi, t, sk, si, wv_, wi_,
                    c2K + ((size_t)j * NPART + part) * KNN,
                    c2I + ((size_t)j * NPART + part) * KNN);
}

// ============ k_final2: merge 80/concept + gather + dot + atomic sum ============
__global__ __launch_bounds__(256) void k_final2(const float* __restrict__ c2K,
                                                const int* __restrict__ c2I,
                                                const float* __restrict__ X,
                                                const float* __restrict__ Cc,
                                                float* __restrict__ out, int bs) {
  int j = blockIdx.x, tid = threadIdx.x;
  const int M2 = NPART * KNN;   // 80
  const float INF = 3.4e38f;

  float bk[KNN]; int bi[KNN];
  #pragma unroll
  for (int q = 0; q < KNN; ++q) { bk[q] = INF; bi[q] = 0x7fffffff; }
  if (tid < M2) {
    bk[0] = c2K[(size_t)j * M2 + tid];
    bi[0] = c2I[(size_t)j * M2 + tid];
  }

  __shared__ float sk[256 * KNN];
  __shared__ int si[256 * KNN];
  __shared__ float wv_[4]; __shared__ int wi_[4];
  __shared__ float topK[KNN]; __shared__ int topIdx[KNN];
  block_merge_top10(bk, bi, tid, sk, si, wv_, wi_, topK, topIdx);

  int lane = tid & 63, wv = tid >> 6;
  float cj = Cc[tid * NC + j];
  float acc = 0.f;
  #pragma unroll
  for (int k = 0; k < KNN; ++k) acc += X[(size_t)topIdx[k] * D + tid] * cj;
  acc = wave_sum(acc);
  __shared__ float rsum[4];
  if (lane == 0) rsum[wv] = acc;
  __syncthreads();
  if (tid == 0)
    atomicAdd(out + (size_t)2 * bs * NCLS,
              (rsum[0] + rsum[1] + rsum[2] + rsum[3]) * (1.0f / (KNN * NC)));
}

extern "C" void kernel_launch(void* const* d_in, const int* in_sizes, int n_in,
                              void* d_out, int out_size, void* d_ws, size_t ws_size,
                              hipStream_t stream) {
  const float* Xb = (const float*)d_in[0]; // train_embedding [bs][D]
  const float* XN = (const float*)d_in[1]; // train_embeddings [N][D]
  const float* C  = (const float*)d_in[2]; // concept [D][NC]
  const float* W  = (const float*)d_in[3]; // W_hx [D][NCLS]
  const float* bv = (const float*)d_in[4]; // b_hx [NCLS]
  float* out = (float*)d_out;

  int bs = in_sizes[0] / D;   // 4096
  int N  = in_sizes[1] / D;   // 200000
  int G  = (N + KROWS - 1) / KROWS;   // 1563

  float* w = (float*)d_ws;
  size_t offT2   = 0;                         // 2560 floats
  size_t offC2K  = 2560;                      // NC*NPART*KNN = 2560
  size_t offC2I  = offC2K + NC * NPART * KNN;
  size_t offCK   = offC2I + NC * NPART * KNN; // NC*G*KNN floats
  size_t offCI   = offCK + (size_t)NC * G * KNN;

  float* T2    = w + offT2;
  float* c2K   = w + offC2K;
  int*   c2I   = (int*)(w + offC2I);
  float* candK = w + offCK;
  int*   candI = (int*)(w + offCI);

  k_key<<<dim3(G), dim3(512), 0, stream>>>(XN, C, candK, candI, N, G);
  k_gramsolve<<<dim3(1), dim3(1024), 0, stream>>>(C, W, T2, out, bs);
  k_pf<<<dim3(PB + NPART * NC), dim3(256), 0, stream>>>(Xb, W, T2, bv, out,
                                                        candK, candI, c2K, c2I, G, bs);
  k_final2<<<dim3(NC), dim3(256), 0, stream>>>(c2K, c2I, XN, C, out, bs);
}